// Round 5
// baseline (331.270 us; speedup 1.0000x reference)
//
#include <hip/hip_runtime.h>
#include <cstdint>

#define N_SAMPLES 16384
#define DIM 2048
#define PDIM 256
#define NB 32
#define NL 100
#define NSEG (NB * NL)

typedef float floatx4 __attribute__((ext_vector_type(4)));
typedef __bf16 bf16x8 __attribute__((ext_vector_type(8)));

__device__ __forceinline__ unsigned short f32_to_bf16(float f) {
    unsigned int u = __float_as_uint(f);
    u += 0x7fffu + ((u >> 16) & 1u);   // round-to-nearest-even
    return (unsigned short)(u >> 16);
}
__device__ __forceinline__ unsigned int pack_bf16x2(float a, float b) {
    return (unsigned int)f32_to_bf16(a) | ((unsigned int)f32_to_bf16(b) << 16);
}

// ---------------------------------------------------------------------------
// prep: Wbf = [W1;W2] -> bf16 (512x2048), bias sum, seg index, zero cnt + SW2
// ---------------------------------------------------------------------------
__global__ __launch_bounds__(256) void prep_kernel(
    const float* __restrict__ W1w, const float* __restrict__ W1b,
    const float* __restrict__ W2w, const float* __restrict__ W2b,
    const int* __restrict__ label, const int* __restrict__ lbatch,
    unsigned short* __restrict__ Wbf, float* __restrict__ bias,
    int* __restrict__ seg, int* __restrict__ cnt, float* __restrict__ SW2)
{
    int i = blockIdx.x * 256 + threadIdx.x;   // grid = PDIM*DIM threads
    Wbf[i]              = f32_to_bf16(W1w[i]);
    Wbf[PDIM * DIM + i] = f32_to_bf16(W2w[i]);
    if (i < PDIM) bias[i] = W1b[i] + W2b[i];
    if (i < N_SAMPLES) seg[i] = lbatch[i] * NL + label[i];
    if (i < NSEG) cnt[i] = 0;
    if (i < NSEG * PDIM / 2) ((float2*)SW2)[i] = make_float2(0.f, 0.f);
}

__global__ __launch_bounds__(256) void hist_kernel(
    const int* __restrict__ seg, int* __restrict__ cnt)
{
    int i = blockIdx.x * 256 + threadIdx.x;
    atomicAdd(&cnt[seg[i]], 1);
}

// ---------------------------------------------------------------------------
// fused GEMM: A = x[16384,2048] f32 (reg-staged -> bf16, XOR-swizzled LDS)
//             B = Wbf[512,2048] bf16 (global_load_lds), BM=64, BN=256, BK=32.
// grid = (2, 256, 2): x = n-half (0: W1 -> outp, 1: W2 -> SW2 atomics),
//                     y = 64-row m-tile, z = K-slice (split-K=2, partials).
// Pipelined 2-barrier loop: A(t+1) reg-loads are issued BETWEEN the barriers
// so their latency drains at the same barrier as B's global_load_lds (one
// combined wait per K-step instead of two sequential ones).
// A LDS is XOR-swizzled (slot ^= (row ^ row>>2) & 3): 8-way -> 2-way (free).
// ---------------------------------------------------------------------------
__global__ __launch_bounds__(256) void gemm_fused_kernel(
    const float* __restrict__ x, const unsigned short* __restrict__ Wbf,
    const int* __restrict__ seg,
    float* __restrict__ outp,          // [2][N_SAMPLES][PDIM] K-slice partials
    float* __restrict__ SW2)
{
    constexpr int BM = 64, BN = 256, BK = 32, KS = 2;
    __shared__ __align__(16) unsigned short ldsA[BM * BK];   // 4 KB
    __shared__ __align__(16) unsigned short ldsB[BN * BK];   // 16 KB
    const int tid = threadIdx.x;
    const int lane = tid & 63;
    const int wave = tid >> 6;                 // wave = n-column group (WC=4)
    const int quad = lane >> 4, l15 = lane & 15;
    const int nhalf = blockIdx.x;              // 0: W1->outp, 1: W2->SW2
    const int m0 = blockIdx.y * BM;
    const int z = blockIdx.z;
    const int k0 = z * (DIM / KS);
    const int nt = (DIM / KS) / BK;            // 32 K-steps
    const int srow = lane >> 2, schunk = lane & 3;
    const int arow = tid >> 2;                 // 0..63
    const int acol = tid & 3;                  // 16B chunk index
    const int aslot_w = acol ^ ((arow ^ (arow >> 2)) & 3);        // write swizzle
    const int aslot_r = quad ^ ((l15 ^ (l15 >> 2)) & 3);          // read swizzle

    floatx4 acc[4][4];
    #pragma unroll
    for (int i = 0; i < 4; ++i)
        #pragma unroll
        for (int j = 0; j < 4; ++j) acc[i][j] = (floatx4){0.f, 0.f, 0.f, 0.f};

    const float* Ax = x + (size_t)(m0 + arow) * DIM + acol * 8;
    const unsigned short* Bbase =
        Wbf + ((size_t)(nhalf * BN) + srow) * DIM + schunk * 8;

    float4 a0 = *(const float4*)(Ax + k0);         // prologue A(0)
    float4 a1 = *(const float4*)(Ax + k0 + 4);

    for (int t = 0; t < nt; ++t) {
        const int kk = k0 + t * BK;
        __syncthreads();                   // all waves done reading tile t-1
        uint4 ao;
        ao.x = pack_bf16x2(a0.x, a0.y);
        ao.y = pack_bf16x2(a0.z, a0.w);
        ao.z = pack_bf16x2(a1.x, a1.y);
        ao.w = pack_bf16x2(a1.z, a1.w);
        *(uint4*)&ldsA[arow * BK + aslot_w * 8] = ao;   // swizzled 16B store
        #pragma unroll
        for (int ch = wave; ch < BN / 16; ch += 4)
            __builtin_amdgcn_global_load_lds(
                (const __attribute__((address_space(1))) void*)(Bbase + (size_t)ch * 16 * DIM + kk),
                (__attribute__((address_space(3))) void*)&ldsB[ch * 16 * BK], 16, 0, 0);
        if (t + 1 < nt) {                  // A(t+1): in flight with B's stage,
            a0 = *(const float4*)(Ax + kk + BK);        // drained at barrier
            a1 = *(const float4*)(Ax + kk + BK + 4);    // below, not at use
        }
        __syncthreads();                   // one combined drain: B stage + A(t+1)

        bf16x8 af[4], bf[4];
        #pragma unroll
        for (int mi = 0; mi < 4; ++mi)
            af[mi] = *(const bf16x8*)&ldsA[(mi * 16 + l15) * BK + aslot_r * 8];
        #pragma unroll
        for (int ni = 0; ni < 4; ++ni)
            bf[ni] = *(const bf16x8*)&ldsB[(wave * 64 + ni * 16 + l15) * BK + quad * 8];
        #pragma unroll
        for (int mi = 0; mi < 4; ++mi)
            #pragma unroll
            for (int ni = 0; ni < 4; ++ni)
                acc[mi][ni] = __builtin_amdgcn_mfma_f32_16x16x32_bf16(
                    af[mi], bf[ni], acc[mi][ni], 0, 0, 0);
    }

    if (nhalf == 0) {
        float* op = outp + (size_t)z * N_SAMPLES * PDIM;
        #pragma unroll
        for (int mi = 0; mi < 4; ++mi) {
            const int rbase = m0 + mi * 16 + quad * 4;
            #pragma unroll
            for (int ni = 0; ni < 4; ++ni) {
                const int col = wave * 64 + ni * 16 + l15;
                #pragma unroll
                for (int r = 0; r < 4; ++r)
                    op[(size_t)(rbase + r) * PDIM + col] = acc[mi][ni][r];
            }
        }
    } else {
        #pragma unroll
        for (int mi = 0; mi < 4; ++mi) {
            const int rbase = m0 + mi * 16 + quad * 4;
            #pragma unroll
            for (int r = 0; r < 4; ++r) {
                const int sr = seg[rbase + r];
                #pragma unroll
                for (int ni = 0; ni < 4; ++ni) {
                    const int col = wave * 64 + ni * 16 + l15;
                    atomicAdd(&SW2[(size_t)sr * PDIM + col], acc[mi][ni][r]);
                }
            }
        }
    }
}

// ---------------------------------------------------------------------------
// finalize: SW2[s,col] <- (BW2[b,col] - SW2[s,col]) / dc   (in place)
// BW2[b] = sum over the batch's 100 label-rows of SW2 (linearity),
// dc = batch count - segment count (zero-guarded like the reference).
// ---------------------------------------------------------------------------
__global__ __launch_bounds__(256) void finalize_kernel(
    float* __restrict__ SW2, const int* __restrict__ cnt)
{
    const int b = blockIdx.x;        // 0..31
    const int col = threadIdx.x;     // 0..255
    int cb = 0;
    #pragma unroll 4
    for (int l = 0; l < NL; ++l) cb += cnt[b * NL + l];
    float tot = 0.f;
    #pragma unroll 4
    for (int l = 0; l < NL; ++l)
        tot += SW2[(size_t)(b * NL + l) * PDIM + col];
    for (int l = 0; l < NL; ++l) {
        const int s = b * NL + l;
        const int dc = cb - cnt[s];
        const float v = SW2[(size_t)s * PDIM + col];
        SW2[(size_t)s * PDIM + col] = (dc > 0) ? (tot - v) / (float)dc : 0.f;
    }
}

// ---------------------------------------------------------------------------
// epilogue: out = outp[0] + outp[1] + bias + SW2[seg]   (float4 per thread)
// ---------------------------------------------------------------------------
__global__ __launch_bounds__(256) void epilogue_kernel(
    float* __restrict__ out, const float* __restrict__ outp,
    const float* __restrict__ SW2, const float* __restrict__ bias,
    const int* __restrict__ seg)
{
    const int idx = blockIdx.x * 256 + threadIdx.x;   // over N*PDIM/4
    const int row = idx >> 6;                         // 64 float4 per row
    const int c = (idx & 63) * 4;
    float4 v0 = ((const float4*)outp)[idx];
    float4 v1 = ((const float4*)outp)[idx + N_SAMPLES * PDIM / 4];
    const float4 b4 = *(const float4*)&bias[c];
    const float4 s4 = *(const float4*)&SW2[(size_t)seg[row] * PDIM + c];
    float4 o;
    o.x = v0.x + v1.x + b4.x + s4.x;
    o.y = v0.y + v1.y + b4.y + s4.y;
    o.z = v0.z + v1.z + b4.z + s4.z;
    o.w = v0.w + v1.w + b4.w + s4.w;
    ((float4*)out)[idx] = o;
}

// ---------------------------------------------------------------------------
extern "C" void kernel_launch(void* const* d_in, const int* in_sizes, int n_in,
                              void* d_out, int out_size, void* d_ws, size_t ws_size,
                              hipStream_t stream)
{
    const float* x      = (const float*)d_in[0];
    const int*   label  = (const int*)d_in[1];
    const int*   lbatch = (const int*)d_in[2];
    const float* W1w    = (const float*)d_in[3];
    const float* W1b    = (const float*)d_in[4];
    const float* W2w    = (const float*)d_in[5];
    const float* W2b    = (const float*)d_in[6];
    float* out = (float*)d_out;

    char* ws = (char*)d_ws;
    size_t off = 0;
    auto alloc = [&](size_t bytes) {
        void* p = ws + off;
        off = (off + bytes + 255) & ~(size_t)255;
        return p;
    };
    float* outp = (float*)alloc((size_t)2 * N_SAMPLES * PDIM * 4);             // 32 MB
    unsigned short* Wbf = (unsigned short*)alloc((size_t)2 * PDIM * DIM * 2);  // 2 MB
    float* SW2  = (float*)alloc((size_t)NSEG * PDIM * 4);                      // 3.3 MB
    float* bias = (float*)alloc(PDIM * 4);
    int*   seg  = (int*)alloc(N_SAMPLES * 4);
    int*   cnt  = (int*)alloc(NSEG * 4);

    prep_kernel<<<PDIM * DIM / 256, 256, 0, stream>>>(
        W1w, W1b, W2w, W2b, label, lbatch, Wbf, bias, seg, cnt, SW2);

    hist_kernel<<<N_SAMPLES / 256, 256, 0, stream>>>(seg, cnt);

    // outp[z] = x@W1^T (K-slice z) ; SW2[s] += (x@W2^T rows of segment s)
    gemm_fused_kernel<<<dim3(2, N_SAMPLES / 64, 2), 256, 0, stream>>>(
        x, Wbf, seg, outp, SW2);

    // SW2[s] <- (batch-total - SW2[s]) / dc   (LOO mean @ W2^T, by linearity)
    finalize_kernel<<<NB, 256, 0, stream>>>(SW2, cnt);

    // out = outp[0] + outp[1] + bias + SW2[seg]
    epilogue_kernel<<<(size_t)N_SAMPLES * PDIM / 4 / 256, 256, 0, stream>>>(
        out, outp, SW2, bias, seg);
}

// Round 6
// 305.213 us; speedup vs baseline: 1.0854x; 1.0854x over previous
//
#include <hip/hip_runtime.h>
#include <cstdint>

#define N_SAMPLES 16384
#define DIM 2048
#define PDIM 256
#define NB 32
#define NL 100
#define NSEG (NB * NL)

typedef float floatx4 __attribute__((ext_vector_type(4)));
typedef __bf16 bf16x8 __attribute__((ext_vector_type(8)));

__device__ __forceinline__ unsigned short f32_to_bf16(float f) {
    unsigned int u = __float_as_uint(f);
    u += 0x7fffu + ((u >> 16) & 1u);   // round-to-nearest-even
    return (unsigned short)(u >> 16);
}
__device__ __forceinline__ unsigned int pack_bf16x2(float a, float b) {
    return (unsigned int)f32_to_bf16(a) | ((unsigned int)f32_to_bf16(b) << 16);
}

// ---------------------------------------------------------------------------
// prep: Wbf = [W1;W2] -> bf16 (512x2048), bias sum, seg index, zero cnt + SW2
// ---------------------------------------------------------------------------
__global__ __launch_bounds__(256) void prep_kernel(
    const float* __restrict__ W1w, const float* __restrict__ W1b,
    const float* __restrict__ W2w, const float* __restrict__ W2b,
    const int* __restrict__ label, const int* __restrict__ lbatch,
    unsigned short* __restrict__ Wbf, float* __restrict__ bias,
    int* __restrict__ seg, int* __restrict__ cnt, float* __restrict__ SW2)
{
    int i = blockIdx.x * 256 + threadIdx.x;   // grid = PDIM*DIM threads
    Wbf[i]              = f32_to_bf16(W1w[i]);
    Wbf[PDIM * DIM + i] = f32_to_bf16(W2w[i]);
    if (i < PDIM) bias[i] = W1b[i] + W2b[i];
    if (i < N_SAMPLES) seg[i] = lbatch[i] * NL + label[i];
    if (i < NSEG) cnt[i] = 0;
    if (i < NSEG * PDIM / 2) ((float2*)SW2)[i] = make_float2(0.f, 0.f);
}

__global__ __launch_bounds__(256) void hist_kernel(
    const int* __restrict__ seg, int* __restrict__ cnt)
{
    int i = blockIdx.x * 256 + threadIdx.x;
    atomicAdd(&cnt[seg[i]], 1);
}

// ---------------------------------------------------------------------------
// xconv: x f32 -> xb bf16, streaming. 32B/lane in, 16B/lane out, coalesced.
// Pure BW-bound (192 MB). Makes A eligible for global_load_lds staging.
// ---------------------------------------------------------------------------
__global__ __launch_bounds__(256) void xconv_kernel(
    const float* __restrict__ x, unsigned short* __restrict__ xb)
{
    const size_t idx = (size_t)blockIdx.x * 256 + threadIdx.x;  // N*D/8 threads
    const float4 a0 = *(const float4*)(x + idx * 8);
    const float4 a1 = *(const float4*)(x + idx * 8 + 4);
    uint4 o;
    o.x = pack_bf16x2(a0.x, a0.y);
    o.y = pack_bf16x2(a0.z, a0.w);
    o.z = pack_bf16x2(a1.x, a1.y);
    o.w = pack_bf16x2(a1.z, a1.w);
    *(uint4*)(xb + idx * 8) = o;
}

// ---------------------------------------------------------------------------
// GEMM (m97 structure, 128x128 tile, 4 waves 2x2, 16 MFMA/K-step, pure
// global_load_lds staging for BOTH operands, classic 2-barrier loop):
//   C[16384, 512] = xb @ [W1;W2]^T
// n-tile 0,1 (cols   0..255): out[row,col] = acc + bias[col]
// n-tile 2,3 (cols 256..511): atomicAdd(SW2[seg[row]][col-256], acc)
// By linearity SW2[s] accumulates (sum of x rows in segment s) @ W2^T.
// ---------------------------------------------------------------------------
__global__ __launch_bounds__(256) void gemm512_kernel(
    const unsigned short* __restrict__ A,    // xb [16384,2048]
    const unsigned short* __restrict__ Wbf,  // [512,2048]
    const float* __restrict__ bias, const int* __restrict__ seg,
    float* __restrict__ out, float* __restrict__ SW2)
{
    constexpr int BM = 128, BN = 128, BK = 32;
    __shared__ __align__(16) unsigned short ldsA[BM * BK];   // 8 KB
    __shared__ __align__(16) unsigned short ldsB[BN * BK];   // 8 KB
    const int tid = threadIdx.x;
    const int lane = tid & 63;
    const int wave = tid >> 6;
    const int wr = wave >> 1, wc = wave & 1;   // 2x2 waves, 64x64 subtile
    const int quad = lane >> 4, l15 = lane & 15;
    const int m0 = blockIdx.x * BM;
    const int n0 = blockIdx.y * BN;            // 0,128,256,384
    const int srow = lane >> 2, schunk = lane & 3;

    floatx4 acc[4][4];
    #pragma unroll
    for (int i = 0; i < 4; ++i)
        #pragma unroll
        for (int j = 0; j < 4; ++j) acc[i][j] = (floatx4){0.f, 0.f, 0.f, 0.f};

    const unsigned short* Abase = A + (size_t)(m0 + srow) * DIM + schunk * 8;
    const unsigned short* Bbase = Wbf + (size_t)(n0 + srow) * DIM + schunk * 8;

    for (int kk = 0; kk < DIM; kk += BK) {
        __syncthreads();
        #pragma unroll
        for (int ch = wave; ch < BM / 16; ch += 4)
            __builtin_amdgcn_global_load_lds(
                (const __attribute__((address_space(1))) void*)(Abase + (size_t)ch * 16 * DIM + kk),
                (__attribute__((address_space(3))) void*)&ldsA[ch * 16 * BK], 16, 0, 0);
        #pragma unroll
        for (int ch = wave; ch < BN / 16; ch += 4)
            __builtin_amdgcn_global_load_lds(
                (const __attribute__((address_space(1))) void*)(Bbase + (size_t)ch * 16 * DIM + kk),
                (__attribute__((address_space(3))) void*)&ldsB[ch * 16 * BK], 16, 0, 0);
        __syncthreads();

        bf16x8 af[4], bf[4];
        #pragma unroll
        for (int mi = 0; mi < 4; ++mi)
            af[mi] = *(const bf16x8*)&ldsA[(wr * 64 + mi * 16 + l15) * BK + quad * 8];
        #pragma unroll
        for (int ni = 0; ni < 4; ++ni)
            bf[ni] = *(const bf16x8*)&ldsB[(wc * 64 + ni * 16 + l15) * BK + quad * 8];
        #pragma unroll
        for (int mi = 0; mi < 4; ++mi)
            #pragma unroll
            for (int ni = 0; ni < 4; ++ni)
                acc[mi][ni] = __builtin_amdgcn_mfma_f32_16x16x32_bf16(
                    af[mi], bf[ni], acc[mi][ni], 0, 0, 0);
    }

    if (n0 < PDIM) {                           // W1 half -> out + bias
        #pragma unroll
        for (int mi = 0; mi < 4; ++mi) {
            const int rbase = m0 + wr * 64 + mi * 16 + quad * 4;
            #pragma unroll
            for (int ni = 0; ni < 4; ++ni) {
                const int col = n0 + wc * 64 + ni * 16 + l15;
                const float bs = bias[col];
                #pragma unroll
                for (int r = 0; r < 4; ++r)
                    out[(size_t)(rbase + r) * PDIM + col] = acc[mi][ni][r] + bs;
            }
        }
    } else {                                   // W2 half -> SW2[seg] atomics
        const int c0 = n0 - PDIM;
        #pragma unroll
        for (int mi = 0; mi < 4; ++mi) {
            const int rbase = m0 + wr * 64 + mi * 16 + quad * 4;
            #pragma unroll
            for (int r = 0; r < 4; ++r) {
                const int sr = seg[rbase + r];
                #pragma unroll
                for (int ni = 0; ni < 4; ++ni) {
                    const int col = c0 + wc * 64 + ni * 16 + l15;
                    atomicAdd(&SW2[(size_t)sr * PDIM + col], acc[mi][ni][r]);
                }
            }
        }
    }
}

// ---------------------------------------------------------------------------
// finalize: SW2[s,col] <- (BW2[b,col] - SW2[s,col]) / dc   (in place)
// BW2[b] = sum over the batch's 100 label-rows of SW2 (linearity),
// dc = batch count - segment count (zero-guarded like the reference).
// ---------------------------------------------------------------------------
__global__ __launch_bounds__(256) void finalize_kernel(
    float* __restrict__ SW2, const int* __restrict__ cnt)
{
    const int b = blockIdx.x;        // 0..31
    const int col = threadIdx.x;     // 0..255
    int cb = 0;
    #pragma unroll 4
    for (int l = 0; l < NL; ++l) cb += cnt[b * NL + l];
    float tot = 0.f;
    #pragma unroll 4
    for (int l = 0; l < NL; ++l)
        tot += SW2[(size_t)(b * NL + l) * PDIM + col];
    for (int l = 0; l < NL; ++l) {
        const int s = b * NL + l;
        const int dc = cb - cnt[s];
        const float v = SW2[(size_t)s * PDIM + col];
        SW2[(size_t)s * PDIM + col] = (dc > 0) ? (tot - v) / (float)dc : 0.f;
    }
}

// ---------------------------------------------------------------------------
// epilogue: out[i,:] += SW2[seg[i],:]   (float4 per thread; bias already in)
// ---------------------------------------------------------------------------
__global__ __launch_bounds__(256) void epilogue_kernel(
    float* __restrict__ out, const float* __restrict__ SW2,
    const int* __restrict__ seg)
{
    const int idx = blockIdx.x * 256 + threadIdx.x;   // over N*PDIM/4
    const int row = idx >> 6;                         // 64 float4 per row
    const int c = (idx & 63) * 4;
    float4 v = ((const float4*)out)[idx];
    const float4 s4 = *(const float4*)&SW2[(size_t)seg[row] * PDIM + c];
    v.x += s4.x; v.y += s4.y; v.z += s4.z; v.w += s4.w;
    ((float4*)out)[idx] = v;
}

// ---------------------------------------------------------------------------
extern "C" void kernel_launch(void* const* d_in, const int* in_sizes, int n_in,
                              void* d_out, int out_size, void* d_ws, size_t ws_size,
                              hipStream_t stream)
{
    const float* x      = (const float*)d_in[0];
    const int*   label  = (const int*)d_in[1];
    const int*   lbatch = (const int*)d_in[2];
    const float* W1w    = (const float*)d_in[3];
    const float* W1b    = (const float*)d_in[4];
    const float* W2w    = (const float*)d_in[5];
    const float* W2b    = (const float*)d_in[6];
    float* out = (float*)d_out;

    char* ws = (char*)d_ws;
    size_t off = 0;
    auto alloc = [&](size_t bytes) {
        void* p = ws + off;
        off = (off + bytes + 255) & ~(size_t)255;
        return p;
    };
    unsigned short* xb  = (unsigned short*)alloc((size_t)N_SAMPLES * DIM * 2); // 64 MB
    unsigned short* Wbf = (unsigned short*)alloc((size_t)2 * PDIM * DIM * 2);  // 2 MB
    float* SW2  = (float*)alloc((size_t)NSEG * PDIM * 4);                      // 3.3 MB
    float* bias = (float*)alloc(PDIM * 4);
    int*   seg  = (int*)alloc(N_SAMPLES * 4);
    int*   cnt  = (int*)alloc(NSEG * 4);

    prep_kernel<<<PDIM * DIM / 256, 256, 0, stream>>>(
        W1w, W1b, W2w, W2b, label, lbatch, Wbf, bias, seg, cnt, SW2);

    hist_kernel<<<N_SAMPLES / 256, 256, 0, stream>>>(seg, cnt);

    xconv_kernel<<<(size_t)N_SAMPLES * DIM / 8 / 256, 256, 0, stream>>>(x, xb);

    // out = xb@W1^T + bias (n-tiles 0,1) ; SW2[s] += xb@W2^T rows (n-tiles 2,3)
    gemm512_kernel<<<dim3(N_SAMPLES / 128, 4), 256, 0, stream>>>(
        xb, Wbf, bias, seg, out, SW2);

    // SW2[s] <- (batch-total - SW2[s]) / dc   (LOO mean @ W2^T, by linearity)
    finalize_kernel<<<NB, 256, 0, stream>>>(SW2, cnt);

    // out += SW2[seg]
    epilogue_kernel<<<(size_t)N_SAMPLES * PDIM / 4 / 256, 256, 0, stream>>>(
        out, SW2, seg);
}